// Round 1
// baseline (267.347 us; speedup 1.0000x reference)
//
#include <hip/hip_runtime.h>
#include <hip/hip_bf16.h>

typedef __bf16 bf16x8 __attribute__((ext_vector_type(8)));
typedef __bf16 bf16x4 __attribute__((ext_vector_type(4)));
typedef float floatx4 __attribute__((ext_vector_type(4)));

#define IC 8
#define RC 8
#define PC 8
#define G_ 4
#define IPG 128
#define OPG 128

#define WROW 136   // padded LDS row stride in bf16 elements (+16B per 256B row)

__global__ __launch_bounds__(256, 2)
void mcsl_kernel(const float* __restrict__ x,
                 const float* __restrict__ W,
                 const float* __restrict__ bias,
                 float* __restrict__ y)
{
    __shared__ __align__(16) __bf16 Wlds[128 * WROW];
    __shared__ float blds[128];

    const int blk = blockIdx.x;
    const int i = blk >> 8;          // channel, 256 blocks per channel
    const int blockRow = blk & 255;  // row-chunk of 128 rows

    // ---- stage W_i (128x128 fp32) -> bf16 LDS, k contiguous, padded rows ----
    const float4* Wsrc = (const float4*)(W + (size_t)i * (OPG * IPG));
    for (int idx = threadIdx.x; idx < (OPG * IPG) / 4; idx += 256) {
        float4 w4 = Wsrc[idx];
        int o  = idx >> 5;           // 32 float4 per row
        int k4 = (idx & 31) << 2;
        bf16x4 wq;
        wq[0] = (__bf16)w4.x; wq[1] = (__bf16)w4.y;
        wq[2] = (__bf16)w4.z; wq[3] = (__bf16)w4.w;
        *(bf16x4*)&Wlds[o * WROW + k4] = wq;
    }
    if (threadIdx.x < 128) blds[threadIdx.x] = bias[i * OPG + threadIdx.x];
    __syncthreads();

    const int lane = threadIdx.x & 63;
    const int wv   = threadIdx.x >> 6;  // wave 0..3
    const int nrow = lane & 15;
    const int quad = lane >> 4;         // 0..3

    // rows m = blockRow*128 .. +127 within channel i; m -> (b_idx, r) with
    // r = (c,p,g) in [0,256). All 128 rows of this block share b_idx.
    const int b_idx  = blockRow >> 1;
    const int r_base = (blockRow & 1) * 128;
    const float* xbase = x + ((size_t)(b_idx * IC + i) * (RC * PC * G_) + r_base) * IPG;
    float*       ybase = y + ((size_t)(b_idx * IC + i) * (RC * PC * G_) + r_base) * OPG;

    // ---- A fragments straight from global, fp32 -> bf16 in-register ----
    // wave handles 32 rows = 2 row-tiles of 16
    bf16x8 afrag[2][4];
    #pragma unroll
    for (int rt = 0; rt < 2; ++rt) {
        const float* rowp = xbase + (size_t)(wv * 32 + rt * 16 + nrow) * IPG;
        #pragma unroll
        for (int ks = 0; ks < 4; ++ks) {
            const float4* p = (const float4*)(rowp + ks * 32 + quad * 8);
            float4 a0 = p[0];
            float4 a1 = p[1];
            bf16x8 af;
            af[0] = (__bf16)a0.x; af[1] = (__bf16)a0.y;
            af[2] = (__bf16)a0.z; af[3] = (__bf16)a0.w;
            af[4] = (__bf16)a1.x; af[5] = (__bf16)a1.y;
            af[6] = (__bf16)a1.z; af[7] = (__bf16)a1.w;
            afrag[rt][ks] = af;
        }
    }

    floatx4 acc[2][8];
    #pragma unroll
    for (int rt = 0; rt < 2; ++rt)
        #pragma unroll
        for (int ct = 0; ct < 8; ++ct)
            acc[rt][ct] = (floatx4){0.f, 0.f, 0.f, 0.f};

    // ---- MFMA main: K=128 = 4 ksteps, N=128 = 8 col tiles ----
    #pragma unroll
    for (int ks = 0; ks < 4; ++ks) {
        #pragma unroll
        for (int ct = 0; ct < 8; ++ct) {
            bf16x8 bfrag = *(const bf16x8*)&Wlds[(ct * 16 + nrow) * WROW + ks * 32 + quad * 8];
            acc[0][ct] = __builtin_amdgcn_mfma_f32_16x16x32_bf16(afrag[0][ks], bfrag, acc[0][ct], 0, 0, 0);
            acc[1][ct] = __builtin_amdgcn_mfma_f32_16x16x32_bf16(afrag[1][ks], bfrag, acc[1][ct], 0, 0, 0);
        }
    }

    // ---- epilogue: bias + store. D layout: col = lane&15, row = quad*4 + reg ----
    #pragma unroll
    for (int rt = 0; rt < 2; ++rt) {
        const int rowl = wv * 32 + rt * 16 + quad * 4;
        #pragma unroll
        for (int ct = 0; ct < 8; ++ct) {
            float bo = blds[ct * 16 + nrow];
            #pragma unroll
            for (int r = 0; r < 4; ++r) {
                ybase[(size_t)(rowl + r) * OPG + ct * 16 + nrow] = acc[rt][ct][r] + bo;
            }
        }
    }
}

extern "C" void kernel_launch(void* const* d_in, const int* in_sizes, int n_in,
                              void* d_out, int out_size, void* d_ws, size_t ws_size,
                              hipStream_t stream) {
    const float* x = (const float*)d_in[0];
    const float* W = (const float*)d_in[1];
    const float* b = (const float*)d_in[2];
    float* y = (float*)d_out;
    // 8 channels x 256 row-chunks of 128 rows
    dim3 grid(2048), block(256);
    hipLaunchKernelGGL(mcsl_kernel, grid, block, 0, stream, x, W, b, y);
}

// Round 2
// 247.709 us; speedup vs baseline: 1.0793x; 1.0793x over previous
//
#include <hip/hip_runtime.h>
#include <hip/hip_bf16.h>

typedef __bf16 bf16x8 __attribute__((ext_vector_type(8)));
typedef __bf16 bf16x4 __attribute__((ext_vector_type(4)));
typedef float floatx4 __attribute__((ext_vector_type(4)));

#define IC 8
#define RC 8
#define PC 8
#define G_ 4
#define IPG 128
#define OPG 128

#define WROW 136   // padded LDS row stride (bf16 elems)
#define XROW 136

// Grid: 1024 blocks = 8 channels (blockIdx&7 -> XCD-pinned W) x 128 batch idx.
// Block owns x[b, i, :, :] : 256 rows x 128 K, contiguous 128 KB.
// Loops 4 chunks of 64 rows; X register-prefetched one chunk ahead -> LDS bf16.
__global__ __launch_bounds__(256, 3)
void mcsl_kernel(const float* __restrict__ x,
                 const float* __restrict__ W,
                 const float* __restrict__ bias,
                 float* __restrict__ y)
{
    __shared__ __align__(16) __bf16 Wlds[128 * WROW];
    __shared__ __align__(16) __bf16 Xlds[64 * XROW];
    __shared__ float blds[128];

    const int tid = threadIdx.x;
    const int i = blockIdx.x & 7;   // channel
    const int b = blockIdx.x >> 3;  // batch index

    const float* xbase = x + ((size_t)(b * (IC * RC) + i * RC)) * (PC * G_ * IPG);
    float*       ybase = y + ((size_t)(b * (IC * RC) + i * RC)) * (PC * G_ * OPG);

    // ---- stage W_i (128x128 fp32 -> bf16 LDS, padded rows) ----
    const float4* Wsrc = (const float4*)(W + (size_t)i * (OPG * IPG));
    #pragma unroll
    for (int it = 0; it < 16; ++it) {
        int idx = tid + it * 256;      // 4096 float4 total
        float4 w4 = Wsrc[idx];
        int o  = idx >> 5;             // 32 float4 per row
        int k4 = (idx & 31) << 2;
        bf16x4 wq;
        wq[0] = (__bf16)w4.x; wq[1] = (__bf16)w4.y;
        wq[2] = (__bf16)w4.z; wq[3] = (__bf16)w4.w;
        *(bf16x4*)&Wlds[o * WROW + k4] = wq;
    }
    if (tid < 128) blds[tid] = bias[i * OPG + tid];

    // ---- prefetch chunk 0 (64 rows x 128 = 32 KB): thread t gets 128 contiguous B
    float4 pf[8];
    {
        const float4* src = (const float4*)xbase;
        #pragma unroll
        for (int j = 0; j < 8; ++j) pf[j] = src[tid * 8 + j];
    }
    {   // write chunk 0 to LDS (bf16)
        const int row = tid >> 2, col0 = (tid & 3) * 32;
        #pragma unroll
        for (int j = 0; j < 4; ++j) {
            float4 a0 = pf[2 * j], a1 = pf[2 * j + 1];
            bf16x8 v;
            v[0] = (__bf16)a0.x; v[1] = (__bf16)a0.y; v[2] = (__bf16)a0.z; v[3] = (__bf16)a0.w;
            v[4] = (__bf16)a1.x; v[5] = (__bf16)a1.y; v[6] = (__bf16)a1.z; v[7] = (__bf16)a1.w;
            *(bf16x8*)&Xlds[row * XROW + col0 + j * 8] = v;
        }
    }
    __syncthreads();

    const int lane = tid & 63;
    const int wv   = tid >> 6;      // wave 0..3 -> rows wv*16..wv*16+15 of chunk
    const int nrow = lane & 15;
    const int quad = lane >> 4;

    #pragma unroll
    for (int c = 0; c < 4; ++c) {
        // ---- issue global prefetch of chunk c+1 (hidden under MFMA below) ----
        if (c < 3) {
            const float4* src = (const float4*)(xbase + (size_t)(c + 1) * 64 * IPG);
            #pragma unroll
            for (int j = 0; j < 8; ++j) pf[j] = src[tid * 8 + j];
        }

        // ---- compute chunk c: wave does 16 rows x 128 cols ----
        bf16x8 af[4];
        #pragma unroll
        for (int ks = 0; ks < 4; ++ks)
            af[ks] = *(const bf16x8*)&Xlds[(wv * 16 + nrow) * XROW + ks * 32 + quad * 8];

        floatx4 acc[8];
        #pragma unroll
        for (int ct = 0; ct < 8; ++ct) acc[ct] = (floatx4){0.f, 0.f, 0.f, 0.f};

        #pragma unroll
        for (int ks = 0; ks < 4; ++ks) {
            #pragma unroll
            for (int ct = 0; ct < 8; ++ct) {
                bf16x8 bfrag = *(const bf16x8*)&Wlds[(ct * 16 + nrow) * WROW + ks * 32 + quad * 8];
                acc[ct] = __builtin_amdgcn_mfma_f32_16x16x32_bf16(af[ks], bfrag, acc[ct], 0, 0, 0);
            }
        }

        // ---- rotate LDS X buffer: all waves done reading chunk c ----
        if (c < 3) {
            __syncthreads();
            const int row = tid >> 2, col0 = (tid & 3) * 32;
            #pragma unroll
            for (int j = 0; j < 4; ++j) {
                float4 a0 = pf[2 * j], a1 = pf[2 * j + 1];
                bf16x8 v;
                v[0] = (__bf16)a0.x; v[1] = (__bf16)a0.y; v[2] = (__bf16)a0.z; v[3] = (__bf16)a0.w;
                v[4] = (__bf16)a1.x; v[5] = (__bf16)a1.y; v[6] = (__bf16)a1.z; v[7] = (__bf16)a1.w;
                *(bf16x8*)&Xlds[row * XROW + col0 + j * 8] = v;
            }
            __syncthreads();
        }

        // ---- epilogue: bias + store chunk c. D: col = lane&15, row = quad*4+r ----
        float* yc = ybase + (size_t)c * 64 * OPG;
        const int rowl = wv * 16 + quad * 4;
        #pragma unroll
        for (int ct = 0; ct < 8; ++ct) {
            float bo = blds[ct * 16 + nrow];
            #pragma unroll
            for (int r = 0; r < 4; ++r)
                yc[(size_t)(rowl + r) * OPG + ct * 16 + nrow] = acc[ct][r] + bo;
        }
    }
}

extern "C" void kernel_launch(void* const* d_in, const int* in_sizes, int n_in,
                              void* d_out, int out_size, void* d_ws, size_t ws_size,
                              hipStream_t stream) {
    const float* x = (const float*)d_in[0];
    const float* W = (const float*)d_in[1];
    const float* b = (const float*)d_in[2];
    float* y = (float*)d_out;
    dim3 grid(1024), block(256);
    hipLaunchKernelGGL(mcsl_kernel, grid, block, 0, stream, x, W, b, y);
}